// Round 12
// baseline (284.152 us; speedup 1.0000x reference)
//
#include <hip/hip_runtime.h>
#include <hip/hip_bf16.h>
#include <math.h>

#define BB 4
#define TT 2048
#define CC 768
#define HH 12
#define HDIM 64
#define C4 3072
#define MM (BB*TT)   // 8192 rows
#define EPSL 1e-5f

typedef __bf16 bf16x8 __attribute__((ext_vector_type(8)));
typedef __bf16 bf16x4 __attribute__((ext_vector_type(4)));
typedef float f32x4 __attribute__((ext_vector_type(4)));

__device__ __forceinline__ ushort f2bf(float f) {
    union { float f; unsigned u; } v; v.f = f;
    unsigned r = v.u + 0x7fffu + ((v.u >> 16) & 1u);
    return (ushort)(r >> 16);
}

__device__ __forceinline__ void glds16(const void* g, void* l) {
    __builtin_amdgcn_global_load_lds(
        (const __attribute__((address_space(1))) void*)g,
        (__attribute__((address_space(3))) void*)l, 16, 0, 0);
}

#define WVM(N) asm volatile("s_waitcnt vmcnt(" #N ")" ::: "memory")
#define WLG0   asm volatile("s_waitcnt lgkmcnt(0)" ::: "memory")

__device__ __forceinline__ void pbar() {
    __builtin_amdgcn_sched_barrier(0);
    __builtin_amdgcn_s_barrier();
    __builtin_amdgcn_sched_barrier(0);
}

// ---------------------------------------------------------------------------
// LayerNorm: one block per row, fp32 in -> bf16 out
// ---------------------------------------------------------------------------
__global__ __launch_bounds__(256) void ln_k(const float* __restrict__ X,
                                            const float* __restrict__ G,
                                            const float* __restrict__ Be,
                                            ushort* __restrict__ O)
{
    int row = blockIdx.x;
    const float* xr = X + (size_t)row * CC;
    int t = threadIdx.x;
    float v0 = xr[t], v1 = xr[t + 256], v2 = xr[t + 512];
    float s  = v0 + v1 + v2;
    float sq = v0*v0 + v1*v1 + v2*v2;
    #pragma unroll
    for (int off = 32; off; off >>= 1) {
        s  += __shfl_xor(s,  off);
        sq += __shfl_xor(sq, off);
    }
    __shared__ float red[8];
    int wv = t >> 6, ln = t & 63;
    if (ln == 0) { red[wv] = s; red[4 + wv] = sq; }
    __syncthreads();
    s  = red[0] + red[1] + red[2] + red[3];
    sq = red[4] + red[5] + red[6] + red[7];
    float mu  = s * (1.0f / CC);
    float var = sq * (1.0f / CC) - mu * mu;
    float rs  = rsqrtf(var + EPSL);
    ushort* orow = O + (size_t)row * CC;
    orow[t]       = f2bf((v0 - mu) * rs * G[t]       + Be[t]);
    orow[t + 256] = f2bf((v1 - mu) * rs * G[t + 256] + Be[t + 256]);
    orow[t + 512] = f2bf((v2 - mu) * rs * G[t + 512] + Be[t + 512]);
}

// ---------------------------------------------------------------------------
// LayerNorm fused with split-K reduce: v = X + P (proj partial); X <- v;
// O <- bf16 LN(v). One block per row.
// ---------------------------------------------------------------------------
__global__ __launch_bounds__(256) void ln_add_k(float* __restrict__ X,
                                                const float* __restrict__ P,
                                                const float* __restrict__ G,
                                                const float* __restrict__ Be,
                                                ushort* __restrict__ O)
{
    int row = blockIdx.x;
    float* xr = X + (size_t)row * CC;
    const float* pr = P + (size_t)row * CC;
    int t = threadIdx.x;
    float v0 = xr[t]       + pr[t];
    float v1 = xr[t + 256] + pr[t + 256];
    float v2 = xr[t + 512] + pr[t + 512];
    xr[t] = v0; xr[t + 256] = v1; xr[t + 512] = v2;
    float s  = v0 + v1 + v2;
    float sq = v0*v0 + v1*v1 + v2*v2;
    #pragma unroll
    for (int off = 32; off; off >>= 1) {
        s  += __shfl_xor(s,  off);
        sq += __shfl_xor(sq, off);
    }
    __shared__ float red[8];
    int wv = t >> 6, ln = t & 63;
    if (ln == 0) { red[wv] = s; red[4 + wv] = sq; }
    __syncthreads();
    s  = red[0] + red[1] + red[2] + red[3];
    sq = red[4] + red[5] + red[6] + red[7];
    float mu  = s * (1.0f / CC);
    float var = sq * (1.0f / CC) - mu * mu;
    float rs  = rsqrtf(var + EPSL);
    ushort* orow = O + (size_t)row * CC;
    orow[t]       = f2bf((v0 - mu) * rs * G[t]       + Be[t]);
    orow[t + 256] = f2bf((v1 - mu) * rs * G[t + 256] + Be[t + 256]);
    orow[t + 512] = f2bf((v2 - mu) * rs * G[t + 512] + Be[t + 512]);
}

// ---------------------------------------------------------------------------
// Split-K reduce: o += p (fp32, float4 grid-stride)
// ---------------------------------------------------------------------------
__global__ __launch_bounds__(256) void addto_k(float* __restrict__ o,
                                               const float* __restrict__ p,
                                               int n4)
{
    int i = blockIdx.x * 256 + threadIdx.x;
    int stride = gridDim.x * 256;
    for (; i < n4; i += stride) {
        float4 a = ((const float4*)o)[i];
        float4 b = ((const float4*)p)[i];
        a.x += b.x; a.y += b.y; a.z += b.z; a.w += b.w;
        ((float4*)o)[i] = a;
    }
}

// ---------------------------------------------------------------------------
// Fused weight repack (single launch): fp32 W -> bf16 W^T via 64x64 LDS tile.
// Block ranges: [0,144) wq | [144,288) wk | [288,432) wv | [432,576) wp |
//               [576,1152) w1 | [1152,1728) w2.
// ---------------------------------------------------------------------------
__global__ __launch_bounds__(256) void repack_all_k(
    const float* __restrict__ wq, const float* __restrict__ wk,
    const float* __restrict__ wvw, const float* __restrict__ wp,
    const float* __restrict__ w1, const float* __restrict__ w2,
    ushort* __restrict__ WTqkv, ushort* __restrict__ WTp,
    ushort* __restrict__ WT1, ushort* __restrict__ WT2)
{
    __shared__ float tl[64][65];
    int blk = blockIdx.x;
    const float* W; ushort* WT;
    int N, outStride, nbx, local, mode;
    if (blk < 576) {
        int wsel = blk / 144; local = blk - wsel * 144; nbx = 12;
        N = 768; outStride = 768;
        mode = wsel < 3 ? 1 : 0;
        W  = wsel == 0 ? wq : (wsel == 1 ? wk : (wsel == 2 ? wvw : wp));
        WT = wsel == 3 ? WTp : WTqkv + (size_t)wsel * 768 * 768;
    } else if (blk < 1152) {
        local = blk - 576; nbx = 48; N = 3072; outStride = 768; mode = 0;
        W = w1; WT = WT1;
    } else {
        local = blk - 1152; nbx = 12; N = 768; outStride = 3072; mode = 0;
        W = w2; WT = WT2;
    }
    int n0 = (local % nbx) * 64, k0 = (local / nbx) * 64;
    int c = threadIdx.x & 63, rr = threadIdx.x >> 6;
    #pragma unroll
    for (int i = 0; i < 16; ++i) {
        int r = i * 4 + rr;
        float v;
        if (mode == 0) v = W[(size_t)(k0 + r) * N + n0 + c];
        else           v = W[((size_t)(n0 >> 6) * CC + k0 + r) * 64 + c];
        tl[r][c] = v;
    }
    __syncthreads();
    #pragma unroll
    for (int i = 0; i < 16; ++i) {
        int r = i * 4 + rr;   // n within tile
        WT[(size_t)(n0 + r) * outStride + k0 + c] = f2bf(tl[c][r]);
    }
}

// ---------------------------------------------------------------------------
// 128x256 bf16 MFMA GEMM (r10 winner, unchanged): BK=32, 512 threads, 8 waves
// each 64x64, triple-buffered LDS (72 KiB), counted WVM(3), XOR swizzle,
// split-K via gridDim.z.
// ---------------------------------------------------------------------------
template<int EPI>
__global__ __launch_bounds__(512, 3) void gemm3s(
    const ushort* __restrict__ A, const ushort* __restrict__ BT,
    int M, int N, int K,
    void* __restrict__ ov0, void* __restrict__ ov1, void* __restrict__ ov2,
    const float* __restrict__ bias0, const float* __restrict__ bias1,
    const float* __restrict__ bias2,
    const float* __restrict__ resid, ushort* __restrict__ obf,
    float* __restrict__ part)
{
    __shared__ ushort lds[3 * 12288];   // slot: A[128][32] @0, B[256][32] @4096

    int nbx = gridDim.x;
    int nwg = nbx * gridDim.y * gridDim.z;
    int orig = (blockIdx.z * gridDim.y + blockIdx.y) * nbx + blockIdx.x;
    int cpx = nwg >> 3;                       // all call sites: nwg % 8 == 0
    int swz = (orig & 7) * cpx + (orig >> 3);
    int zi = swz / (nbx * gridDim.y);
    int rem = swz - zi * nbx * gridDim.y;
    int bn = rem % nbx, bm = rem / nbx;

    int tid = threadIdx.x;
    int lane = tid & 63;
    int w = tid >> 6;
    int wrow = (w >> 2) * 64, wcol = (w & 3) * 64;
    int fr = lane & 15, kh = lane >> 4;
    int rxor = ((fr >> 1) & 3) * 8;           // read-side swizzle (elements)

    const size_t aR0 = (size_t)bm * 128;
    const size_t bR0 = (size_t)bn * 256;
    const int Ksl = K / (int)gridDim.z;
    const int koff = zi * Ksl;
    const int nt = Ksl >> 5;                  // >= 12 at all call sites

    int srow = tid >> 2;                      // staging row 0..127
    int scol = (tid & 3) * 8;                 // physical LDS col (elements)
    int sxor = scol ^ (((tid >> 3) & 3) * 8); // pre-swizzled source col

    f32x4 acc[4][4] = {};

    auto stage = [&](int slot, int t) {
        int kb = koff + (t << 5) + sxor;
        ushort* As = lds + slot * 12288;
        glds16(A  + (aR0 + srow) * K + kb,       As + srow * 32 + scol);
        glds16(BT + (bR0 + srow) * K + kb,       As + 4096 + srow * 32 + scol);
        glds16(BT + (bR0 + 128 + srow) * K + kb, As + 4096 + (128 + srow) * 32 + scol);
    };

    // ---- prologue: stage tiles 0 and 1 ----
    stage(0, 0);
    stage(1, 1);
    WVM(3);            // tile 0 complete (tile 1's 3 may remain in flight)
    pbar();

    // ---- main loop: 1 phase per K-tile, prefetch 2 tiles ahead ----
    int slot = 0;
    for (int t = 0; t < nt; ++t) {
        const ushort* As = lds + slot * 12288;
        const ushort* Bs = As + 4096;
        bf16x8 aF[4], bF[4];
        #pragma unroll
        for (int i = 0; i < 4; ++i)
            aF[i] = *(const bf16x8*)&As[(wrow + i * 16 + fr) * 32 + ((kh * 8) ^ rxor)];
        #pragma unroll
        for (int j = 0; j < 4; ++j)
            bF[j] = *(const bf16x8*)&Bs[(wcol + j * 16 + fr) * 32 + ((kh * 8) ^ rxor)];
        if (t + 2 < nt) {
            int ns = slot + 2; if (ns >= 3) ns -= 3;
            stage(ns, t + 2);
        }
        __builtin_amdgcn_s_setprio(1);
        #pragma unroll
        for (int i = 0; i < 4; ++i)
            #pragma unroll
            for (int j = 0; j < 4; ++j)
                acc[i][j] = __builtin_amdgcn_mfma_f32_16x16x32_bf16(aF[i], bF[j], acc[i][j], 0, 0, 0);
        __builtin_amdgcn_s_setprio(0);
        // ledger: outstanding = t+1's 3 (issued last phase) + t+2's 3 (now)
        if (t + 2 < nt) { WVM(3); } else { WVM(0); }
        WLG0;
        pbar();
        slot = slot + 1 == 3 ? 0 : slot + 1;
    }

    // ---- epilogue: C/D layout col = lane&15, row = (lane>>4)*4 + r ----
    if (gridDim.z > 1 && zi > 0) {
        #pragma unroll
        for (int i = 0; i < 4; ++i) {
            int row0 = bm * 128 + wrow + i * 16 + kh * 4;
            #pragma unroll
            for (int j = 0; j < 4; ++j) {
                int col = bn * 256 + wcol + j * 16 + fr;
                #pragma unroll
                for (int r = 0; r < 4; ++r)
                    part[(size_t)(row0 + r) * N + col] = acc[i][j][r];
            }
        }
    } else if (EPI == 1) {
        int seg = bn / 3;
        ushort* op = (ushort*)(seg == 0 ? ov0 : (seg == 1 ? ov1 : ov2));
        const float* bsp = seg == 0 ? bias0 : (seg == 1 ? bias1 : bias2);
        int cb = (bn - seg * 3) * 256 + wcol;    // multiple of 64
        int h = cb >> 6;
        #pragma unroll
        for (int i = 0; i < 4; ++i) {
            int row0 = bm * 128 + wrow + i * 16 + kh * 4;
            int b = row0 >> 11;
            int t0 = row0 & (TT - 1);
            #pragma unroll
            for (int j = 0; j < 4; ++j) {
                int d = j * 16 + fr;
                float bsv = bsp[h * 64 + d];
                #pragma unroll
                for (int r = 0; r < 4; ++r)
                    op[((size_t)(b * HH + h) * TT + t0 + r) * 64 + d] =
                        f2bf(acc[i][j][r] + bsv);
            }
        }
    } else if (EPI == 2) {
        float* o0 = (float*)ov0;
        #pragma unroll
        for (int i = 0; i < 4; ++i) {
            int row0 = bm * 128 + wrow + i * 16 + kh * 4;
            #pragma unroll
            for (int j = 0; j < 4; ++j) {
                int col = bn * 256 + wcol + j * 16 + fr;
                float bsv = bias0[col];
                #pragma unroll
                for (int r = 0; r < 4; ++r) {
                    size_t idx = (size_t)(row0 + r) * N + col;
                    o0[idx] = acc[i][j][r] + bsv + resid[idx];
                }
            }
        }
    } else {  // EPI 3
        #pragma unroll
        for (int i = 0; i < 4; ++i) {
            int row0 = bm * 128 + wrow + i * 16 + kh * 4;
            #pragma unroll
            for (int j = 0; j < 4; ++j) {
                int col = bn * 256 + wcol + j * 16 + fr;
                float bsv = bias0[col];
                #pragma unroll
                for (int r = 0; r < 4; ++r) {
                    float v = fmaxf(acc[i][j][r] + bsv, 0.f);
                    obf[(size_t)(row0 + r) * N + col] = f2bf(v);
                }
            }
        }
    }
}

// ---------------------------------------------------------------------------
// V transpose: bf16 [B,H,T,64] -> [B,H,64,T] (per (b,h), 64x64 LDS tiles)
// ---------------------------------------------------------------------------
__global__ __launch_bounds__(256) void vtrans_k(const ushort* __restrict__ V,
                                                ushort* __restrict__ Vt)
{
    __shared__ ushort tl[64][72];
    int blk = blockIdx.x;
    int tt = blk & 31, bh = blk >> 5;
    size_t base = (size_t)bh * TT * 64;
    int t0 = tt * 64;
    int e = threadIdx.x;
    int rr = e >> 3, cc8 = (e & 7) * 8;
    #pragma unroll
    for (int p = 0; p < 2; ++p) {
        int t = p * 32 + rr;
        *(uint4*)&tl[t][cc8] = *(const uint4*)&V[base + (size_t)(t0 + t) * 64 + cc8];
    }
    __syncthreads();
    #pragma unroll
    for (int p = 0; p < 2; ++p) {
        int d = p * 32 + rr;
        ushort tmp[8];
        #pragma unroll
        for (int i = 0; i < 8; ++i) tmp[i] = tl[cc8 + i][d];
        *(uint4*)&Vt[base + (size_t)d * TT + t0 + cc8] = *(uint4*)tmp;
    }
}

// ---------------------------------------------------------------------------
// Flash attention, bf16 MFMA. Block = 512 threads / 8 waves / 128 q-rows
// (wave w owns rows q0+16w..+15): 24 waves/CU static (75% cap, was 37.5%),
// and each staged K/V tile feeds 8 waves (stage traffic per q-row halves).
// Grid 768 = 48 bh x 16 q-tiles, heavy-first (qt descending) + XCD chunking.
// Single barrier per KV tile, double-buffered K/V slots, reg prefetch (T14),
// XOR swizzle (0 conflicts), skip-max fast path, exp2 softmax, deferred sum.
// ---------------------------------------------------------------------------
__global__ __launch_bounds__(512) void attn_k(const ushort* __restrict__ Q,
                                              const ushort* __restrict__ Kb,
                                              const ushort* __restrict__ Vt,
                                              ushort* __restrict__ Ob)
{
    __shared__ ushort Kl[2][64][64];
    __shared__ ushort Vl[2][64][64];
    __shared__ ushort Pl[8][16][68];

    int orig = blockIdx.x;                 // nwg = 768
    int swz = (orig & 7) * 96 + (orig >> 3);
    int bh = swz >> 4;
    int qt = 15 - (swz & 15);              // heavy tiles dispatch first
    int b = bh / HH, h = bh - b * HH;
    int q0 = qt * 128;
    int nt = 2 * qt + 2;                   // kv tiles (64-wide) covering q0+127
    int tid = threadIdx.x, lane = tid & 63, w = tid >> 6;
    int c = lane & 15, g = lane >> 4;
    size_t base = (size_t)bh * TT * 64;
    int srow = tid >> 3;                   // 0..63 (full tile row coverage)
    int scol = (tid & 7) * 8;
    int sw = scol ^ ((srow & 7) * 8);      // swizzled LDS col
    int rxk = (c & 7) * 8;                 // read-XOR (rows j*16+c)
    const float LOG2E = 1.44269504088896340736f;

    int wrow = w * 16;                     // wave's first q row (local)

    // wave's Q A-fragments (16 rows x 64 d), scaled by log2e, in regs
    bf16x8 aq[2];
    #pragma unroll
    for (int kc = 0; kc < 2; ++kc) {
        bf16x8 raw = *(const bf16x8*)&Q[base + (size_t)(q0 + wrow + c) * 64 + kc * 32 + g * 8];
        #pragma unroll
        for (int e = 0; e < 8; ++e)
            raw[e] = (__bf16)((float)raw[e] * LOG2E);
        aq[kc] = raw;
    }

    f32x4 oa[4] = {};
    float mrun[4] = {-INFINITY, -INFINITY, -INFINITY, -INFINITY};
    float lrun[4] = {0.f, 0.f, 0.f, 0.f};

    // prologue: tile 0 -> slot 0; tile 1 -> regs
    {
        uint4 a0 = *(const uint4*)&Kb[base + (size_t)srow * 64 + scol];
        uint4 a1 = *(const uint4*)&Vt[base + (size_t)srow * TT + scol];
        *(uint4*)&Kl[0][srow][sw] = a0;
        *(uint4*)&Vl[0][srow][sw] = a1;
    }
    uint4 kr, vr;
    {
        kr = *(const uint4*)&Kb[base + (size_t)(64 + srow) * 64 + scol];
        vr = *(const uint4*)&Vt[base + (size_t)srow * TT + 64 + scol];
    }
    __syncthreads();

    for (int t = 0; t < nt; ++t) {
        int cur = t & 1;
        int kv0 = t * 64;
        if (t + 1 < nt) {
            int nxt = cur ^ 1;
            *(uint4*)&Kl[nxt][srow][sw] = kr;
            *(uint4*)&Vl[nxt][srow][sw] = vr;
            if (t + 2 < nt) {
                int kn = (t + 2) * 64;
                kr = *(const uint4*)&Kb[base + (size_t)(kn + srow) * 64 + scol];
                vr = *(const uint4*)&Vt[base + (size_t)srow * TT + kn + scol];
            }
        }

        if (kv0 <= q0 + wrow + 15) {   // wave-uniform: any unmasked rows?
            // S[16 q][64 kv] = Qs @ K^T  (log2-domain scores)
            f32x4 sa[4] = {};
            #pragma unroll
            for (int kc = 0; kc < 2; ++kc)
                #pragma unroll
                for (int j = 0; j < 4; ++j) {
                    bf16x8 kf = *(const bf16x8*)&Kl[cur][j * 16 + c][(kc * 32 + g * 8) ^ rxk];
                    sa[j] = __builtin_amdgcn_mfma_f32_16x16x32_bf16(aq[kc], kf, sa[j], 0, 0, 0);
                }

            if (kv0 + 63 > q0 + wrow) {   // tile straddles this wave's diagonal
                #pragma unroll
                for (int j = 0; j < 4; ++j)
                    #pragma unroll
                    for (int r = 0; r < 4; ++r)
                        if (kv0 + j * 16 + c > q0 + wrow + g * 4 + r) sa[j][r] = -1e30f;
            }

            // skip-max fast path: per-lane max only, no cross-lane reduce
            float vlmax = sa[0][0];
            #pragma unroll
            for (int j = 0; j < 4; ++j)
                #pragma unroll
                for (int r = 0; r < 4; ++r) vlmax = fmaxf(vlmax, sa[j][r]);
            float mmin = fminf(fminf(mrun[0], mrun[1]), fminf(mrun[2], mrun[3]));
            if (!__all(vlmax <= mmin + 11.5f)) {
                #pragma unroll
                for (int r = 0; r < 4; ++r) {
                    float m0 = fmaxf(fmaxf(sa[0][r], sa[1][r]), fmaxf(sa[2][r], sa[3][r]));
                    #pragma unroll
                    for (int off = 8; off; off >>= 1) m0 = fmaxf(m0, __shfl_xor(m0, off));
                    float mnew = fmaxf(mrun[r], m0);
                    float sc = __builtin_amdgcn_exp2f(mrun[r] - mnew);
                    lrun[r] *= sc;
                    #pragma unroll
                    for (int j = 0; j < 4; ++j) oa[j][r] *= sc;
                    mrun[r] = mnew;
                }
            }
            // exps + per-lane partial sums
            #pragma unroll
            for (int r = 0; r < 4; ++r) {
                float ps = 0.f;
                #pragma unroll
                for (int j = 0; j < 4; ++j) {
                    float p = __builtin_amdgcn_exp2f(sa[j][r] - mrun[r]);
                    sa[j][r] = p;
                    ps += p;
                }
                lrun[r] += ps;
            }

            // P -> bf16 -> per-wave LDS (C/D layout -> A-frag layout)
            #pragma unroll
            for (int r = 0; r < 4; ++r)
                #pragma unroll
                for (int j = 0; j < 4; ++j)
                    Pl[w][g * 4 + r][j * 16 + c] = (ushort)__builtin_bit_cast(unsigned short, (__bf16)sa[j][r]);

            bf16x8 pf[2];
            #pragma unroll
            for (int kc = 0; kc < 2; ++kc) {
                bf16x4 lo = *(const bf16x4*)&Pl[w][c][kc * 32 + g * 8];
                bf16x4 hi = *(const bf16x4*)&Pl[w][c][kc * 32 + g * 8 + 4];
                pf[kc] = __builtin_shufflevector(lo, hi, 0, 1, 2, 3, 4, 5, 6, 7);
            }

            // O[16 q][64 d] += P @ V
            #pragma unroll
            for (int kc = 0; kc < 2; ++kc)
                #pragma unroll
                for (int j = 0; j < 4; ++j) {
                    bf16x8 vf = *(const bf16x8*)&Vl[cur][j * 16 + c][(kc * 32 + g * 8) ^ rxk];
                    oa[j] = __builtin_amdgcn_mfma_f32_16x16x32_bf16(pf[kc], vf, oa[j], 0, 0, 0);
                }
        }

        __syncthreads();   // single barrier per tile
    }

    // final row-sum of deferred partials, then normalize + store
    float inv[4];
    #pragma unroll
    for (int r = 0; r < 4; ++r) {
        float l = lrun[r];
        #pragma unroll
        for (int off = 8; off; off >>= 1) l += __shfl_xor(l, off);
        inv[r] = 1.0f / l;
    }
    size_t orow = (size_t)b * TT + q0 + wrow;
    #pragma unroll
    for (int j = 0; j < 4; ++j)
        #pragma unroll
        for (int r = 0; r < 4; ++r) {
            float v = oa[j][r] * inv[r];
            Ob[(orow + g * 4 + r) * CC + h * 64 + j * 16 + c] = f2bf(v);
        }
}

// ---------------------------------------------------------------------------
// Orchestration. ws layout (ushorts), S = MM*CC = 6291456:
//   WTqkv [2304*768]  WTp [768*768]  WT1 [3072*768]  WT2 [768*3072]
//   hbf [S]  attnb [S]  qb [S]  kb [S]  vb [S]  vtb [S]
//   midb [MM*3072] aliases qb..vtb (dead after attention)
//   part_proj f32 [MM*768] aliases qb+kb; part_w2 f32 aliases hbf+attnb
// ---------------------------------------------------------------------------
extern "C" void kernel_launch(void* const* d_in, const int* in_sizes, int n_in,
                              void* d_out, int out_size, void* d_ws, size_t ws_size,
                              hipStream_t stream)
{
    const float* x   = (const float*)d_in[0];
    const float* wq  = (const float*)d_in[1];
    const float* bq  = (const float*)d_in[2];
    const float* wk  = (const float*)d_in[3];
    const float* bk  = (const float*)d_in[4];
    const float* wvw = (const float*)d_in[5];
    const float* bv  = (const float*)d_in[6];
    const float* wp  = (const float*)d_in[7];
    const float* bp  = (const float*)d_in[8];
    const float* w1  = (const float*)d_in[9];
    const float* b1  = (const float*)d_in[10];
    const float* w2  = (const float*)d_in[11];
    const float* b2  = (const float*)d_in[12];
    const float* g1  = (const float*)d_in[13];
    const float* be1 = (const float*)d_in[14];
    const float* g2  = (const float*)d_in[15];
    const float* be2 = (const float*)d_in[16];

    float* out = (float*)d_out;
    const size_t S = (size_t)MM * CC;

    ushort* wsu   = (ushort*)d_ws;
    ushort* WTqkv = wsu;
    ushort* WTp   = WTqkv + (size_t)2304 * 768;
    ushort* WT1   = WTp   + (size_t)768 * 768;
    ushort* WT2   = WT1   + (size_t)3072 * 768;
    ushort* hbf   = WT2   + (size_t)768 * 3072;
    ushort* attnb = hbf   + S;
    ushort* qb    = attnb + S;
    ushort* kb    = qb + S;
    ushort* vb    = kb + S;
    ushort* vtb   = vb + S;
    ushort* midb  = qb;                 // [8192][3072] bf16 == qb..vtb
    float*  part_proj = (float*)qb;     // f32 [8192][768] == qb+kb bytes
    float*  part_w2   = (float*)hbf;    // f32 [8192][768] == hbf+attnb bytes

    repack_all_k<<<1728, 256, 0, stream>>>(wq, wk, wvw, wp, w1, w2,
                                           WTqkv, WTp, WT1, WT2);

    // --- attention sublayer ---
    ln_k<<<MM, 256, 0, stream>>>(x, g1, be1, hbf);
    gemm3s<1><<<dim3(9, 64, 1), 512, 0, stream>>>(hbf, WTqkv, MM, 2304, CC,
        qb, kb, vb, bq, bk, bv, nullptr, nullptr, nullptr);
    vtrans_k<<<48 * 32, 256, 0, stream>>>(vb, vtb);
    attn_k<<<48 * 16, 512, 0, stream>>>(qb, kb, vtb, attnb);
    // proj: split-K=2, z=1 partial -> part_proj (qb region, dead after attn)
    gemm3s<2><<<dim3(3, 64, 2), 512, 0, stream>>>(attnb, WTp, MM, CC, CC,
        out, nullptr, nullptr, bp, nullptr, nullptr, x, nullptr, part_proj);

    // --- MLP sublayer (ln2 fuses the proj split-K reduce) ---
    ln_add_k<<<MM, 256, 0, stream>>>(out, part_proj, g2, be2, hbf);
    gemm3s<3><<<dim3(12, 64, 1), 512, 0, stream>>>(hbf, WT1, MM, C4, CC,
        nullptr, nullptr, nullptr, b1, nullptr, nullptr, nullptr, midb, nullptr);
    // w2: split-K=2, z=1 partial -> part_w2 (hbf/attnb region, dead after w1)
    gemm3s<2><<<dim3(3, 64, 2), 512, 0, stream>>>(midb, WT2, MM, CC, C4,
        out, nullptr, nullptr, b2, nullptr, nullptr, out, nullptr, part_w2);
    addto_k<<<2048, 256, 0, stream>>>(out, part_w2, MM * CC / 4);
}

// Round 13
// 277.638 us; speedup vs baseline: 1.0235x; 1.0235x over previous
//
#include <hip/hip_runtime.h>
#include <hip/hip_bf16.h>
#include <math.h>

#define BB 4
#define TT 2048
#define CC 768
#define HH 12
#define HDIM 64
#define C4 3072
#define MM (BB*TT)   // 8192 rows
#define EPSL 1e-5f

typedef __bf16 bf16x8 __attribute__((ext_vector_type(8)));
typedef __bf16 bf16x4 __attribute__((ext_vector_type(4)));
typedef float f32x4 __attribute__((ext_vector_type(4)));

__device__ __forceinline__ ushort f2bf(float f) {
    union { float f; unsigned u; } v; v.f = f;
    unsigned r = v.u + 0x7fffu + ((v.u >> 16) & 1u);
    return (ushort)(r >> 16);
}

__device__ __forceinline__ void glds16(const void* g, void* l) {
    __builtin_amdgcn_global_load_lds(
        (const __attribute__((address_space(1))) void*)g,
        (__attribute__((address_space(3))) void*)l, 16, 0, 0);
}

#define WVM(N) asm volatile("s_waitcnt vmcnt(" #N ")" ::: "memory")
#define WLG0   asm volatile("s_waitcnt lgkmcnt(0)" ::: "memory")

__device__ __forceinline__ void pbar() {
    __builtin_amdgcn_sched_barrier(0);
    __builtin_amdgcn_s_barrier();
    __builtin_amdgcn_sched_barrier(0);
}

// ---------------------------------------------------------------------------
// LayerNorm: one block per row, fp32 in -> bf16 out
// ---------------------------------------------------------------------------
__global__ __launch_bounds__(256) void ln_k(const float* __restrict__ X,
                                            const float* __restrict__ G,
                                            const float* __restrict__ Be,
                                            ushort* __restrict__ O)
{
    int row = blockIdx.x;
    const float* xr = X + (size_t)row * CC;
    int t = threadIdx.x;
    float v0 = xr[t], v1 = xr[t + 256], v2 = xr[t + 512];
    float s  = v0 + v1 + v2;
    float sq = v0*v0 + v1*v1 + v2*v2;
    #pragma unroll
    for (int off = 32; off; off >>= 1) {
        s  += __shfl_xor(s,  off);
        sq += __shfl_xor(sq, off);
    }
    __shared__ float red[8];
    int wv = t >> 6, ln = t & 63;
    if (ln == 0) { red[wv] = s; red[4 + wv] = sq; }
    __syncthreads();
    s  = red[0] + red[1] + red[2] + red[3];
    sq = red[4] + red[5] + red[6] + red[7];
    float mu  = s * (1.0f / CC);
    float var = sq * (1.0f / CC) - mu * mu;
    float rs  = rsqrtf(var + EPSL);
    ushort* orow = O + (size_t)row * CC;
    orow[t]       = f2bf((v0 - mu) * rs * G[t]       + Be[t]);
    orow[t + 256] = f2bf((v1 - mu) * rs * G[t + 256] + Be[t + 256]);
    orow[t + 512] = f2bf((v2 - mu) * rs * G[t + 512] + Be[t + 512]);
}

// ---------------------------------------------------------------------------
// LayerNorm fused with split-K reduce: v = X + P (proj partial); X <- v;
// O <- bf16 LN(v). One block per row.
// ---------------------------------------------------------------------------
__global__ __launch_bounds__(256) void ln_add_k(float* __restrict__ X,
                                                const float* __restrict__ P,
                                                const float* __restrict__ G,
                                                const float* __restrict__ Be,
                                                ushort* __restrict__ O)
{
    int row = blockIdx.x;
    float* xr = X + (size_t)row * CC;
    const float* pr = P + (size_t)row * CC;
    int t = threadIdx.x;
    float v0 = xr[t]       + pr[t];
    float v1 = xr[t + 256] + pr[t + 256];
    float v2 = xr[t + 512] + pr[t + 512];
    xr[t] = v0; xr[t + 256] = v1; xr[t + 512] = v2;
    float s  = v0 + v1 + v2;
    float sq = v0*v0 + v1*v1 + v2*v2;
    #pragma unroll
    for (int off = 32; off; off >>= 1) {
        s  += __shfl_xor(s,  off);
        sq += __shfl_xor(sq, off);
    }
    __shared__ float red[8];
    int wv = t >> 6, ln = t & 63;
    if (ln == 0) { red[wv] = s; red[4 + wv] = sq; }
    __syncthreads();
    s  = red[0] + red[1] + red[2] + red[3];
    sq = red[4] + red[5] + red[6] + red[7];
    float mu  = s * (1.0f / CC);
    float var = sq * (1.0f / CC) - mu * mu;
    float rs  = rsqrtf(var + EPSL);
    ushort* orow = O + (size_t)row * CC;
    orow[t]       = f2bf((v0 - mu) * rs * G[t]       + Be[t]);
    orow[t + 256] = f2bf((v1 - mu) * rs * G[t + 256] + Be[t + 256]);
    orow[t + 512] = f2bf((v2 - mu) * rs * G[t + 512] + Be[t + 512]);
}

// ---------------------------------------------------------------------------
// Split-K reduce: o += p (fp32, float4 grid-stride)
// ---------------------------------------------------------------------------
__global__ __launch_bounds__(256) void addto_k(float* __restrict__ o,
                                               const float* __restrict__ p,
                                               int n4)
{
    int i = blockIdx.x * 256 + threadIdx.x;
    int stride = gridDim.x * 256;
    for (; i < n4; i += stride) {
        float4 a = ((const float4*)o)[i];
        float4 b = ((const float4*)p)[i];
        a.x += b.x; a.y += b.y; a.z += b.z; a.w += b.w;
        ((float4*)o)[i] = a;
    }
}

// ---------------------------------------------------------------------------
// Fused weight repack (single launch): fp32 W -> bf16 W^T via 64x64 LDS tile.
// ---------------------------------------------------------------------------
__global__ __launch_bounds__(256) void repack_all_k(
    const float* __restrict__ wq, const float* __restrict__ wk,
    const float* __restrict__ wvw, const float* __restrict__ wp,
    const float* __restrict__ w1, const float* __restrict__ w2,
    ushort* __restrict__ WTqkv, ushort* __restrict__ WTp,
    ushort* __restrict__ WT1, ushort* __restrict__ WT2)
{
    __shared__ float tl[64][65];
    int blk = blockIdx.x;
    const float* W; ushort* WT;
    int N, outStride, nbx, local, mode;
    if (blk < 576) {
        int wsel = blk / 144; local = blk - wsel * 144; nbx = 12;
        N = 768; outStride = 768;
        mode = wsel < 3 ? 1 : 0;
        W  = wsel == 0 ? wq : (wsel == 1 ? wk : (wsel == 2 ? wvw : wp));
        WT = wsel == 3 ? WTp : WTqkv + (size_t)wsel * 768 * 768;
    } else if (blk < 1152) {
        local = blk - 576; nbx = 48; N = 3072; outStride = 768; mode = 0;
        W = w1; WT = WT1;
    } else {
        local = blk - 1152; nbx = 12; N = 768; outStride = 3072; mode = 0;
        W = w2; WT = WT2;
    }
    int n0 = (local % nbx) * 64, k0 = (local / nbx) * 64;
    int c = threadIdx.x & 63, rr = threadIdx.x >> 6;
    #pragma unroll
    for (int i = 0; i < 16; ++i) {
        int r = i * 4 + rr;
        float v;
        if (mode == 0) v = W[(size_t)(k0 + r) * N + n0 + c];
        else           v = W[((size_t)(n0 >> 6) * CC + k0 + r) * 64 + c];
        tl[r][c] = v;
    }
    __syncthreads();
    #pragma unroll
    for (int i = 0; i < 16; ++i) {
        int r = i * 4 + rr;   // n within tile
        WT[(size_t)(n0 + r) * outStride + k0 + c] = f2bf(tl[c][r]);
    }
}

// ---------------------------------------------------------------------------
// 128x256 bf16 MFMA GEMM (r10 winner): BK=32, 512 threads, 8 waves each
// 64x64, triple-buffered LDS (72 KiB), counted WVM(3), XOR swizzle, split-K
// via gridDim.z. EPI 1 additionally TRANSPOSES the V segment in-epilogue
// (through the now-idle GEMM LDS) and writes Vt [B,H,64,T] directly --
// replaces the former vtrans kernel (saves a launch + 25 MB of traffic).
// ---------------------------------------------------------------------------
template<int EPI>
__global__ __launch_bounds__(512, 3) void gemm3s(
    const ushort* __restrict__ A, const ushort* __restrict__ BT,
    int M, int N, int K,
    void* __restrict__ ov0, void* __restrict__ ov1, void* __restrict__ ov2,
    const float* __restrict__ bias0, const float* __restrict__ bias1,
    const float* __restrict__ bias2,
    const float* __restrict__ resid, ushort* __restrict__ obf,
    float* __restrict__ part)
{
    __shared__ ushort lds[3 * 12288];   // slot: A[128][32] @0, B[256][32] @4096

    int nbx = gridDim.x;
    int nwg = nbx * gridDim.y * gridDim.z;
    int orig = (blockIdx.z * gridDim.y + blockIdx.y) * nbx + blockIdx.x;
    int cpx = nwg >> 3;                       // all call sites: nwg % 8 == 0
    int swz = (orig & 7) * cpx + (orig >> 3);
    int zi = swz / (nbx * gridDim.y);
    int rem = swz - zi * nbx * gridDim.y;
    int bn = rem % nbx, bm = rem / nbx;

    int tid = threadIdx.x;
    int lane = tid & 63;
    int w = tid >> 6;
    int wrow = (w >> 2) * 64, wcol = (w & 3) * 64;
    int fr = lane & 15, kh = lane >> 4;
    int rxor = ((fr >> 1) & 3) * 8;           // read-side swizzle (elements)

    const size_t aR0 = (size_t)bm * 128;
    const size_t bR0 = (size_t)bn * 256;
    const int Ksl = K / (int)gridDim.z;
    const int koff = zi * Ksl;
    const int nt = Ksl >> 5;                  // >= 12 at all call sites

    int srow = tid >> 2;                      // staging row 0..127
    int scol = (tid & 3) * 8;                 // physical LDS col (elements)
    int sxor = scol ^ (((tid >> 3) & 3) * 8); // pre-swizzled source col

    f32x4 acc[4][4] = {};

    auto stage = [&](int slot, int t) {
        int kb = koff + (t << 5) + sxor;
        ushort* As = lds + slot * 12288;
        glds16(A  + (aR0 + srow) * K + kb,       As + srow * 32 + scol);
        glds16(BT + (bR0 + srow) * K + kb,       As + 4096 + srow * 32 + scol);
        glds16(BT + (bR0 + 128 + srow) * K + kb, As + 4096 + (128 + srow) * 32 + scol);
    };

    // ---- prologue: stage tiles 0 and 1 ----
    stage(0, 0);
    stage(1, 1);
    WVM(3);
    pbar();

    // ---- main loop: 1 phase per K-tile, prefetch 2 tiles ahead ----
    int slot = 0;
    for (int t = 0; t < nt; ++t) {
        const ushort* As = lds + slot * 12288;
        const ushort* Bs = As + 4096;
        bf16x8 aF[4], bF[4];
        #pragma unroll
        for (int i = 0; i < 4; ++i)
            aF[i] = *(const bf16x8*)&As[(wrow + i * 16 + fr) * 32 + ((kh * 8) ^ rxor)];
        #pragma unroll
        for (int j = 0; j < 4; ++j)
            bF[j] = *(const bf16x8*)&Bs[(wcol + j * 16 + fr) * 32 + ((kh * 8) ^ rxor)];
        if (t + 2 < nt) {
            int ns = slot + 2; if (ns >= 3) ns -= 3;
            stage(ns, t + 2);
        }
        __builtin_amdgcn_s_setprio(1);
        #pragma unroll
        for (int i = 0; i < 4; ++i)
            #pragma unroll
            for (int j = 0; j < 4; ++j)
                acc[i][j] = __builtin_amdgcn_mfma_f32_16x16x32_bf16(aF[i], bF[j], acc[i][j], 0, 0, 0);
        __builtin_amdgcn_s_setprio(0);
        if (t + 2 < nt) { WVM(3); } else { WVM(0); }
        WLG0;
        pbar();
        slot = slot + 1 == 3 ? 0 : slot + 1;
    }

    // ---- epilogue: C/D layout col = lane&15, row = (lane>>4)*4 + r ----
    if (gridDim.z > 1 && zi > 0) {
        #pragma unroll
        for (int i = 0; i < 4; ++i) {
            int row0 = bm * 128 + wrow + i * 16 + kh * 4;
            #pragma unroll
            for (int j = 0; j < 4; ++j) {
                int col = bn * 256 + wcol + j * 16 + fr;
                #pragma unroll
                for (int r = 0; r < 4; ++r)
                    part[(size_t)(row0 + r) * N + col] = acc[i][j][r];
            }
        }
    } else if (EPI == 1) {
        int seg = bn / 3;
        if (seg < 2) {
            // q / k: bf16 [B,H,T,64] scatter (+bias)
            ushort* op = (ushort*)(seg == 0 ? ov0 : ov1);
            const float* bsp = seg == 0 ? bias0 : bias1;
            int cb = (bn - seg * 3) * 256 + wcol;    // multiple of 64
            int h = cb >> 6;
            #pragma unroll
            for (int i = 0; i < 4; ++i) {
                int row0 = bm * 128 + wrow + i * 16 + kh * 4;
                int b = row0 >> 11;
                int t0 = row0 & (TT - 1);
                #pragma unroll
                for (int j = 0; j < 4; ++j) {
                    int d = j * 16 + fr;
                    float bsv = bsp[h * 64 + d];
                    #pragma unroll
                    for (int r = 0; r < 4; ++r)
                        op[((size_t)(b * HH + h) * TT + t0 + r) * 64 + d] =
                            f2bf(acc[i][j][r] + bsv);
                }
            }
        } else {
            // V: transpose via LDS -> Vt bf16 [B,H,64,T] (+bias)
            ushort* vt = (ushort*)ov2;
            int cb = (bn - 6) * 256 + wcol;
            int h = cb >> 6;                     // head for this wave
            ushort* tw = lds + w * 4608;         // per-wave 64x72 region
            #pragma unroll
            for (int i = 0; i < 4; ++i)
                #pragma unroll
                for (int j = 0; j < 4; ++j) {
                    float bsv = bias2[h * 64 + j * 16 + fr];
                    #pragma unroll
                    for (int r = 0; r < 4; ++r)
                        tw[(i * 16 + kh * 4 + r) * 72 + j * 16 + fr] =
                            f2bf(acc[i][j][r] + bsv);
                }
            __syncthreads();
            int row0 = bm * 128 + wrow;          // first t of this wave's tile
            int b = row0 >> 11;
            int t0 = row0 & (TT - 1);
            size_t voff = ((size_t)(b * HH + h) * 64 + lane) * TT;  // d = lane
            #pragma unroll
            for (int ch = 0; ch < 8; ++ch) {
                ushort v8[8];
                #pragma unroll
                for (int e = 0; e < 8; ++e)
                    v8[e] = tw[(ch * 8 + e) * 72 + lane];
                *(uint4*)&vt[voff + t0 + ch * 8] = *(uint4*)v8;
            }
        }
    } else if (EPI == 2) {
        float* o0 = (float*)ov0;
        #pragma unroll
        for (int i = 0; i < 4; ++i) {
            int row0 = bm * 128 + wrow + i * 16 + kh * 4;
            #pragma unroll
            for (int j = 0; j < 4; ++j) {
                int col = bn * 256 + wcol + j * 16 + fr;
                float bsv = bias0[col];
                #pragma unroll
                for (int r = 0; r < 4; ++r) {
                    size_t idx = (size_t)(row0 + r) * N + col;
                    o0[idx] = acc[i][j][r] + bsv + resid[idx];
                }
            }
        }
    } else {  // EPI 3
        #pragma unroll
        for (int i = 0; i < 4; ++i) {
            int row0 = bm * 128 + wrow + i * 16 + kh * 4;
            #pragma unroll
            for (int j = 0; j < 4; ++j) {
                int col = bn * 256 + wcol + j * 16 + fr;
                float bsv = bias0[col];
                #pragma unroll
                for (int r = 0; r < 4; ++r) {
                    float v = fmaxf(acc[i][j][r] + bsv, 0.f);
                    obf[(size_t)(row0 + r) * N + col] = f2bf(v);
                }
            }
        }
    }
}

// ---------------------------------------------------------------------------
// Flash attention (r11 winner, exact revert): bf16 MFMA, paired q-tiles
// (i,31-i => 33 tiles/block), 4 waves/256 threads, double-buffered K/V slots
// with single barrier per tile, T14 reg prefetch, XOR swizzle (0 conflicts),
// skip-max fast path, exp2-domain softmax, deferred sum reduce.
// ---------------------------------------------------------------------------
__global__ __launch_bounds__(256) void attn_k(const ushort* __restrict__ Q,
                                              const ushort* __restrict__ Kb,
                                              const ushort* __restrict__ Vt,
                                              ushort* __restrict__ Ob)
{
    __shared__ ushort Kl[2][64][64];
    __shared__ ushort Vl[2][64][64];
    __shared__ ushort Pl[4][16][68];

    int orig = blockIdx.x;                 // nwg = 768
    int swz = (orig & 7) * 96 + (orig >> 3);
    int pair = swz & 15;
    int bh = swz >> 4;
    int b = bh / HH, h = bh - b * HH;
    int tid = threadIdx.x, lane = tid & 63, w = tid >> 6;
    int c = lane & 15, g = lane >> 4;
    size_t base = (size_t)bh * TT * 64;
    int srow = tid >> 3;                   // 0..31 (row and row+32)
    int scol = (tid & 7) * 8;
    int sw0 = scol ^ ((srow & 7) * 8);
    int sw1 = scol ^ (((srow + 32) & 7) * 8);
    int rxk = (c & 7) * 8;
    const float LOG2E = 1.44269504088896340736f;

    #pragma unroll
    for (int sel = 0; sel < 2; ++sel) {
        int qt = sel ? (31 - pair) : pair;
        int q0 = qt * 64;
        int nt = qt + 1;

        bf16x8 aq[2];
        #pragma unroll
        for (int kc = 0; kc < 2; ++kc) {
            bf16x8 raw = *(const bf16x8*)&Q[base + (size_t)(q0 + w * 16 + c) * 64 + kc * 32 + g * 8];
            #pragma unroll
            for (int e = 0; e < 8; ++e)
                raw[e] = (__bf16)((float)raw[e] * LOG2E);
            aq[kc] = raw;
        }

        f32x4 oa[4] = {};
        float mrun[4] = {-INFINITY, -INFINITY, -INFINITY, -INFINITY};
        float lrun[4] = {0.f, 0.f, 0.f, 0.f};

        // prologue: tile 0 -> regs -> slot 0; tile 1 -> regs; publish
        {
            uint4 a0 = *(const uint4*)&Kb[base + (size_t)srow * 64 + scol];
            uint4 a1 = *(const uint4*)&Kb[base + (size_t)(32 + srow) * 64 + scol];
            uint4 a2 = *(const uint4*)&Vt[base + (size_t)srow * TT + scol];
            uint4 a3 = *(const uint4*)&Vt[base + (size_t)(32 + srow) * TT + scol];
            *(uint4*)&Kl[0][srow][sw0]      = a0;
            *(uint4*)&Kl[0][32 + srow][sw1] = a1;
            *(uint4*)&Vl[0][srow][sw0]      = a2;
            *(uint4*)&Vl[0][32 + srow][sw1] = a3;
        }
        uint4 k0r, k1r, v0r, v1r;
        if (nt > 1) {
            k0r = *(const uint4*)&Kb[base + (size_t)(64 + srow) * 64 + scol];
            k1r = *(const uint4*)&Kb[base + (size_t)(96 + srow) * 64 + scol];
            v0r = *(const uint4*)&Vt[base + (size_t)srow * TT + 64 + scol];
            v1r = *(const uint4*)&Vt[base + (size_t)(32 + srow) * TT + 64 + scol];
        }
        __syncthreads();

        for (int t = 0; t < nt; ++t) {
            int cur = t & 1;
            if (t + 1 < nt) {
                int nxt = cur ^ 1;
                *(uint4*)&Kl[nxt][srow][sw0]      = k0r;
                *(uint4*)&Kl[nxt][32 + srow][sw1] = k1r;
                *(uint4*)&Vl[nxt][srow][sw0]      = v0r;
                *(uint4*)&Vl[nxt][32 + srow][sw1] = v1r;
                if (t + 2 < nt) {
                    int kn = (t + 2) * 64;
                    k0r = *(const uint4*)&Kb[base + (size_t)(kn + srow) * 64 + scol];
                    k1r = *(const uint4*)&Kb[base + (size_t)(kn + 32 + srow) * 64 + scol];
                    v0r = *(const uint4*)&Vt[base + (size_t)srow * TT + kn + scol];
                    v1r = *(const uint4*)&Vt[base + (size_t)(32 + srow) * TT + kn + scol];
                }
            }

            f32x4 sa[4] = {};
            #pragma unroll
            for (int kc = 0; kc < 2; ++kc)
                #pragma unroll
                for (int j = 0; j < 4; ++j) {
                    bf16x8 kf = *(const bf16x8*)&Kl[cur][j * 16 + c][(kc * 32 + g * 8) ^ rxk];
                    sa[j] = __builtin_amdgcn_mfma_f32_16x16x32_bf16(aq[kc], kf, sa[j], 0, 0, 0);
                }

            if (t == nt - 1) {
                #pragma unroll
                for (int j = 0; j < 4; ++j)
                    #pragma unroll
                    for (int r = 0; r < 4; ++r)
                        if (j * 16 + c > w * 16 + g * 4 + r) sa[j][r] = -1e30f;
            }

            float vlmax = sa[0][0];
            #pragma unroll
            for (int j = 0; j < 4; ++j)
                #pragma unroll
                for (int r = 0; r < 4; ++r) vlmax = fmaxf(vlmax, sa[j][r]);
            float mmin = fminf(fminf(mrun[0], mrun[1]), fminf(mrun[2], mrun[3]));
            if (!__all(vlmax <= mmin + 11.5f)) {
                #pragma unroll
                for (int r = 0; r < 4; ++r) {
                    float m0 = fmaxf(fmaxf(sa[0][r], sa[1][r]), fmaxf(sa[2][r], sa[3][r]));
                    #pragma unroll
                    for (int off = 8; off; off >>= 1) m0 = fmaxf(m0, __shfl_xor(m0, off));
                    float mnew = fmaxf(mrun[r], m0);
                    float sc = __builtin_amdgcn_exp2f(mrun[r] - mnew);
                    lrun[r] *= sc;
                    #pragma unroll
                    for (int j = 0; j < 4; ++j) oa[j][r] *= sc;
                    mrun[r] = mnew;
                }
            }
            #pragma unroll
            for (int r = 0; r < 4; ++r) {
                float ps = 0.f;
                #pragma unroll
                for (int j = 0; j < 4; ++j) {
                    float p = __builtin_amdgcn_exp2f(sa[j][r] - mrun[r]);
                    sa[j][r] = p;
                    ps += p;
                }
                lrun[r] += ps;
            }

            #pragma unroll
            for (int r = 0; r < 4; ++r)
                #pragma unroll
                for (int j = 0; j < 4; ++j)
                    Pl[w][g * 4 + r][j * 16 + c] = (ushort)__builtin_bit_cast(unsigned short, (__bf16)sa[j][r]);

            bf16x8 pf[2];
            #pragma unroll
            for (int kc = 0; kc < 2; ++kc) {
                bf16x4 lo = *(const bf16x4*)&Pl[w][c][kc * 32 + g * 8];
                bf16x4 hi = *(const bf16x4*)&Pl[w][c][kc * 32 + g * 8 + 4];
                pf[kc] = __builtin_shufflevector(lo, hi, 0, 1, 2, 3, 4, 5, 6, 7);
            }

            #pragma unroll
            for (int kc = 0; kc < 2; ++kc)
                #pragma unroll
                for (int j = 0; j < 4; ++j) {
                    bf16x8 vf = *(const bf16x8*)&Vl[cur][j * 16 + c][(kc * 32 + g * 8) ^ rxk];
                    oa[j] = __builtin_amdgcn_mfma_f32_16x16x32_bf16(pf[kc], vf, oa[j], 0, 0, 0);
                }

            __syncthreads();   // single barrier per tile
        }

        float inv[4];
        #pragma unroll
        for (int r = 0; r < 4; ++r) {
            float l = lrun[r];
            #pragma unroll
            for (int off = 8; off; off >>= 1) l += __shfl_xor(l, off);
            inv[r] = 1.0f / l;
        }
        size_t orow = (size_t)b * TT + q0 + w * 16;
        #pragma unroll
        for (int j = 0; j < 4; ++j)
            #pragma unroll
            for (int r = 0; r < 4; ++r) {
                float v = oa[j][r] * inv[r];
                Ob[(orow + g * 4 + r) * CC + h * 64 + j * 16 + c] = f2bf(v);
            }
    }
}

// ---------------------------------------------------------------------------
// Orchestration. ws layout (ushorts), S = MM*CC = 6291456:
//   WTqkv [2304*768]  WTp [768*768]  WT1 [3072*768]  WT2 [768*3072]
//   hbf [S]  attnb [S]  qb [S]  kb [S]  vb [S](unused)  vtb [S]
//   midb [MM*3072] aliases qb..vtb (dead after attention)
//   part_proj f32 [MM*768] aliases qb+kb; part_w2 f32 aliases hbf+attnb
// ---------------------------------------------------------------------------
extern "C" void kernel_launch(void* const* d_in, const int* in_sizes, int n_in,
                              void* d_out, int out_size, void* d_ws, size_t ws_size,
                              hipStream_t stream)
{
    const float* x   = (const float*)d_in[0];
    const float* wq  = (const float*)d_in[1];
    const float* bq  = (const float*)d_in[2];
    const float* wk  = (const float*)d_in[3];
    const float* bk  = (const float*)d_in[4];
    const float* wvw = (const float*)d_in[5];
    const float* bv  = (const float*)d_in[6];
    const float* wp  = (const float*)d_in[7];
    const float* bp  = (const float*)d_in[8];
    const float* w1  = (const float*)d_in[9];
    const float* b1  = (const float*)d_in[10];
    const float* w2  = (const float*)d_in[11];
    const float* b2  = (const float*)d_in[12];
    const float* g1  = (const float*)d_in[13];
    const float* be1 = (const float*)d_in[14];
    const float* g2  = (const float*)d_in[15];
    const float* be2 = (const float*)d_in[16];

    float* out = (float*)d_out;
    const size_t S = (size_t)MM * CC;

    ushort* wsu   = (ushort*)d_ws;
    ushort* WTqkv = wsu;
    ushort* WTp   = WTqkv + (size_t)2304 * 768;
    ushort* WT1   = WTp   + (size_t)768 * 768;
    ushort* WT2   = WT1   + (size_t)3072 * 768;
    ushort* hbf   = WT2   + (size_t)768 * 3072;
    ushort* attnb = hbf   + S;
    ushort* qb    = attnb + S;
    ushort* kb    = qb + S;
    ushort* vb    = kb + S;   // unused (V goes straight to vtb)
    ushort* vtb   = vb + S;
    ushort* midb  = qb;                 // [8192][3072] bf16 == qb..vtb
    float*  part_proj = (float*)qb;     // f32 [8192][768] == qb+kb bytes
    float*  part_w2   = (float*)hbf;    // f32 [8192][768] == hbf+attnb bytes

    repack_all_k<<<1728, 256, 0, stream>>>(wq, wk, wvw, wp, w1, w2,
                                           WTqkv, WTp, WT1, WT2);

    // --- attention sublayer ---
    ln_k<<<MM, 256, 0, stream>>>(x, g1, be1, hbf);
    gemm3s<1><<<dim3(9, 64, 1), 512, 0, stream>>>(hbf, WTqkv, MM, 2304, CC,
        qb, kb, vtb, bq, bk, bv, nullptr, nullptr, nullptr);
    attn_k<<<48 * 16, 256, 0, stream>>>(qb, kb, vtb, attnb);
    // proj: split-K=2, z=1 partial -> part_proj (qb region, dead after attn)
    gemm3s<2><<<dim3(3, 64, 2), 512, 0, stream>>>(attnb, WTp, MM, CC, CC,
        out, nullptr, nullptr, bp, nullptr, nullptr, x, nullptr, part_proj);

    // --- MLP sublayer (ln2 fuses the proj split-K reduce) ---
    ln_add_k<<<MM, 256, 0, stream>>>(out, part_proj, g2, be2, hbf);
    gemm3s<3><<<dim3(12, 64, 1), 512, 0, stream>>>(hbf, WT1, MM, C4, CC,
        nullptr, nullptr, nullptr, b1, nullptr, nullptr, nullptr, midb, nullptr);
    // w2: split-K=2, z=1 partial -> part_w2 (hbf/attnb region, dead after w1)
    gemm3s<2><<<dim3(3, 64, 2), 512, 0, stream>>>(midb, WT2, MM, CC, C4,
        out, nullptr, nullptr, b2, nullptr, nullptr, out, nullptr, part_w2);
    addto_k<<<2048, 256, 0, stream>>>(out, part_w2, MM * CC / 4);
}